// Round 17
// baseline (4733.654 us; speedup 1.0000x reference)
//
#include <hip/hip_runtime.h>
#include <math.h>

#define B    32
#define H    1024
#define EMB  512
#define V    32000
#define SOS  1

// ws float offsets. x/h fp32 state: [b][k] (per-lane float4 reads).
#define OFF_XG  0             // [B][EMB] = 16384
#define OFF_HA  16384         // [B][H] = 32768
#define OFF_HB  49152
#define OFF_P   81920         // float4[32][500] = 64000 floats
#define OFF_C   145920        // T*B
#define OFF_HHI 147968        // short[H*B] packed (16384 floats)
#define OFF_HLO 164352
#define OFF_W3  180736        // float[1024][384][3][4] = 4718592
#define OFF_WHI 4899328       // short[V*H] (16384000 floats)
#define OFF_WLO 21283328      // ends 37667328 floats (150.7 MB)

#define NEG_INF (-3.0e38f)

typedef float f4v   __attribute__((ext_vector_type(4)));
typedef short short8v __attribute__((ext_vector_type(8)));
typedef float f32x4 __attribute__((ext_vector_type(4)));

#define MF(a,b,c) c = __builtin_amdgcn_mfma_f32_16x16x32_bf16(a, b, c, 0, 0, 0)

__device__ __forceinline__ unsigned short rnb(float x) {
    unsigned u = __float_as_uint(x);
    unsigned r = u + 0x7FFFu + ((u >> 16) & 1u);
    return (unsigned short)(r >> 16);
}
__device__ __forceinline__ float bfh(unsigned short s) {
    return __uint_as_float(((unsigned)s) << 16);
}
__device__ __forceinline__ void sm_merge(float& m, float& l, int& a,
                                         float om, float ol, int oa)
{
    const bool take = (om > m) || (om == m && oa < a);
    const float mn = take ? om : m;
    const int   an = take ? oa : a;
    l = l * expf(m - mn) + ol * expf(om - mn);
    m = mn; a = an;
}

// ---------------------------------------------------------------- INIT
__global__ void k_init(const float* __restrict__ ih, const float* __restrict__ emb,
                       const float* __restrict__ wout,
                       const float* __restrict__ wih, const float* __restrict__ whh,
                       float* __restrict__ ws)
{
    const size_t idx = (size_t)blockIdx.x * blockDim.x + threadIdx.x;
    const size_t stride = (size_t)gridDim.x * blockDim.x;

    for (size_t i = idx; i < EMB * B; i += stride) {
        const int k = (int)(i >> 5), b = (int)(i & 31);
        ws[OFF_XG + b * EMB + k] = tanhf(emb[(size_t)SOS * EMB + k]);
    }
    short* Hhi = (short*)(ws + OFF_HHI);
    short* Hlo = (short*)(ws + OFF_HLO);
    for (size_t i = idx; i < H * B; i += stride) {
        const int j = (int)(i >> 5), b = (int)(i & 31);
        const float hv = ih[(size_t)b * H + j];
        ws[OFF_HA + b * H + j] = hv;
        const unsigned short hi = rnb(hv);
        const int pidx = ((j >> 3) * 32 + b) * 8 + (j & 7);
        Hhi[pidx] = (short)hi;
        Hlo[pidx] = (short)rnb(hv - bfh(hi));
    }
    // gate weights interleaved: W3[j][kq][g][e], k = kq*4+e over [x(512) | h(1024)]
    float* W3 = ws + OFF_W3;
    for (size_t i = idx; i < (size_t)H * 384 * 12; i += stride) {
        const int j   = (int)(i / (384 * 12));
        const int rem = (int)(i % (384 * 12));
        const int kq  = rem / 12;
        const int g   = (rem % 12) >> 2;
        const int e   = rem & 3;
        const int k   = kq * 4 + e;
        W3[i] = (k < EMB) ? wih[(size_t)(g * H + j) * EMB + k]
                          : whh[(size_t)(g * H + j) * H + (k - EMB)];
    }
    short* Whi = (short*)(ws + OFF_WHI);
    short* Wlo = (short*)(ws + OFF_WLO);
    for (size_t i = idx; i < (size_t)V * H; i += stride) {
        const float x = wout[i];
        const unsigned short hi = rnb(x);
        Whi[i] = (short)hi;
        Wlo[i] = (short)rnb(x - bfh(hi));
    }
}

// ---------------------------------------------------------------- GRU (fp32, W3 layout, [b][k] state)
__global__ __launch_bounds__(1024) void k_gru(
    const float* __restrict__ xG, const float* __restrict__ hold,
    const float* __restrict__ W3,
    const float* __restrict__ bih, const float* __restrict__ bhh,
    float* __restrict__ hnew, short* __restrict__ Hhi, short* __restrict__ Hlo)
{
    const int t   = threadIdx.x;
    const int blk = blockIdx.x;
    __shared__ float sred[4 * 1152];

    const int ks = t >> 7;
    const int pl = t & 127;
    const int p  = blk * 128 + pl;
    const int b  = p & 31;
    const int j  = p >> 5;

    float ar = 0.f, az = 0.f, ain = 0.f, ahn = 0.f;
    const int k0 = ks * 192, k1 = k0 + 192;

    // x-part
    const int xe = (k1 < EMB) ? k1 : EMB;
    {
        const float* w3 = W3 + ((size_t)j * 384 + (k0 >> 2)) * 12;
        for (int k = k0; k < xe; k += 4, w3 += 12) {
            const float4 u  = *(const float4*)&xG[b * EMB + k];
            const float4 w0 = *(const float4*)&w3[0];
            const float4 w1 = *(const float4*)&w3[4];
            const float4 w2 = *(const float4*)&w3[8];
            ar  = fmaf(w0.x, u.x, fmaf(w0.y, u.y, fmaf(w0.z, u.z, fmaf(w0.w, u.w, ar))));
            az  = fmaf(w1.x, u.x, fmaf(w1.y, u.y, fmaf(w1.z, u.z, fmaf(w1.w, u.w, az))));
            ain = fmaf(w2.x, u.x, fmaf(w2.y, u.y, fmaf(w2.z, u.z, fmaf(w2.w, u.w, ain))));
        }
    }
    // h-part
    const int hs = (k0 > EMB) ? k0 : EMB;
    {
        const float* w3 = W3 + ((size_t)j * 384 + (hs >> 2)) * 12;
        for (int k = hs; k < k1; k += 4, w3 += 12) {
            const int kh = k - EMB;
            const float4 u  = *(const float4*)&hold[b * H + kh];
            const float4 w0 = *(const float4*)&w3[0];
            const float4 w1 = *(const float4*)&w3[4];
            const float4 w2 = *(const float4*)&w3[8];
            ar  = fmaf(w0.x, u.x, fmaf(w0.y, u.y, fmaf(w0.z, u.z, fmaf(w0.w, u.w, ar))));
            az  = fmaf(w1.x, u.x, fmaf(w1.y, u.y, fmaf(w1.z, u.z, fmaf(w1.w, u.w, az))));
            ahn = fmaf(w2.x, u.x, fmaf(w2.y, u.y, fmaf(w2.z, u.z, fmaf(w2.w, u.w, ahn))));
        }
    }

    sred[0 * 1152 + pl * 9 + ks] = ar;
    sred[1 * 1152 + pl * 9 + ks] = az;
    sred[2 * 1152 + pl * 9 + ks] = ain;
    sred[3 * 1152 + pl * 9 + ks] = ahn;
    __syncthreads();

    if (t < 128) {
        const int pp = blk * 128 + t;
        const int bb = pp & 31, jj = pp >> 5;
        float s0 = 0.f, s1 = 0.f, s2 = 0.f, s3 = 0.f;
#pragma unroll
        for (int q = 0; q < 8; ++q) {
            s0 += sred[0 * 1152 + t * 9 + q];
            s1 += sred[1 * 1152 + t * 9 + q];
            s2 += sred[2 * 1152 + t * 9 + q];
            s3 += sred[3 * 1152 + t * 9 + q];
        }
        float gr  = s0 + bih[jj]         + bhh[jj];
        float gz  = s1 + bih[H + jj]     + bhh[H + jj];
        float gin = s2 + bih[2 * H + jj];
        float ghn = s3 + bhh[2 * H + jj];
        float r = 1.f / (1.f + expf(-gr));
        float z = 1.f / (1.f + expf(-gz));
        float n = tanhf(gin + r * ghn);   // r multiplies hh-part only
        const float ho = hold[bb * H + jj];
        const float hv = (1.f - z) * n + z * ho;
        hnew[bb * H + jj] = hv;
        const unsigned short hi = rnb(hv);
        const unsigned short lo = rnb(hv - bfh(hi));
        const int pidx = ((jj >> 3) * 32 + bb) * 8 + (jj & 7);
        Hhi[pidx] = (short)hi;
        Hlo[pidx] = (short)lo;
    }
}

// ---------------------------------------------------------------- PROJ via bf16-MFMA (3-pass) — R15 body
__global__ __launch_bounds__(512, 4) void k_proj(
    const short* __restrict__ Whi, const short* __restrict__ Wlo,
    const short* __restrict__ Hhi, const short* __restrict__ Hlo,
    const float* __restrict__ bout, float* __restrict__ orow,
    float4* __restrict__ P)
{
    __shared__ float Red[4 * 32 * 33];
    __shared__ float Dt[32 * 68];
    __shared__ float bl[64];
    __shared__ float pm[2][32], pls[2][32];
    __shared__ int   pa[2][32];

    const int t   = threadIdx.x;
    const int blk = blockIdx.x;
    const int r0  = blk * 64;
    const int w   = t >> 6;
    const int mh  = w >> 2;
    const int kq  = w & 3;
    const int l   = t & 63;
    const int lr  = l & 15;
    const int lg  = l >> 4;

    if (t < 64) bl[t] = bout[r0 + t];

    const short* pAh = Whi + (size_t)(r0 + mh * 32 + lr) * H + lg * 8;
    const short* pAl = Wlo + (size_t)(r0 + mh * 32 + lr) * H + lg * 8;
    const short* pBh = Hhi + ((size_t)lg * 32 + lr) * 8;
    const short* pBl = Hlo + ((size_t)lg * 32 + lr) * 8;

    f32x4 acc00 = {0.f, 0.f, 0.f, 0.f};
    f32x4 acc01 = {0.f, 0.f, 0.f, 0.f};
    f32x4 acc10 = {0.f, 0.f, 0.f, 0.f};
    f32x4 acc11 = {0.f, 0.f, 0.f, 0.f};

#pragma unroll 2
    for (int i = 0; i < 8; ++i) {
        const int c = 4 * i + kq;
        const short8v a0h = *(const short8v*)(pAh + c * 32);
        const short8v a0l = *(const short8v*)(pAl + c * 32);
        const short8v a1h = *(const short8v*)(pAh + 16 * H + c * 32);
        const short8v a1l = *(const short8v*)(pAl + 16 * H + c * 32);
        const short8v b0h = *(const short8v*)(pBh + c * 1024);
        const short8v b0l = *(const short8v*)(pBl + c * 1024);
        const short8v b1h = *(const short8v*)(pBh + c * 1024 + 128);
        const short8v b1l = *(const short8v*)(pBl + c * 1024 + 128);
        MF(a0h, b0h, acc00); MF(a0h, b0l, acc00); MF(a0l, b0h, acc00);
        MF(a0h, b1h, acc01); MF(a0h, b1l, acc01); MF(a0l, b1h, acc01);
        MF(a1h, b0h, acc10); MF(a1h, b0l, acc10); MF(a1l, b0h, acc10);
        MF(a1h, b1h, acc11); MF(a1h, b1l, acc11); MF(a1l, b1h, acc11);
    }

    if (kq >= 2) {
        float* rp = Red + (mh * 2 + (kq - 2)) * 1056;
#pragma unroll
        for (int mt = 0; mt < 2; ++mt)
#pragma unroll
            for (int r = 0; r < 4; ++r) {
                const int row = mt * 16 + lg * 4 + r;
                rp[row * 33 + lr]      = mt ? acc10[r] : acc00[r];
                rp[row * 33 + 16 + lr] = mt ? acc11[r] : acc01[r];
            }
    }
    __syncthreads();
    if (kq < 2) {
        const float* rp = Red + (mh * 2 + kq) * 1056;
#pragma unroll
        for (int mt = 0; mt < 2; ++mt)
#pragma unroll
            for (int r = 0; r < 4; ++r) {
                const int row = mt * 16 + lg * 4 + r;
                const float e0 = rp[row * 33 + lr];
                const float e1 = rp[row * 33 + 16 + lr];
                if (mt) { acc10[r] += e0; acc11[r] += e1; }
                else    { acc00[r] += e0; acc01[r] += e1; }
            }
    }
    __syncthreads();
    if (kq == 1) {
        float* rp = Red + mh * 2 * 1056;
#pragma unroll
        for (int mt = 0; mt < 2; ++mt)
#pragma unroll
            for (int r = 0; r < 4; ++r) {
                const int row = mt * 16 + lg * 4 + r;
                rp[row * 33 + lr]      = mt ? acc10[r] : acc00[r];
                rp[row * 33 + 16 + lr] = mt ? acc11[r] : acc01[r];
            }
    }
    __syncthreads();

    if (kq == 0) {
        const float* rp = Red + mh * 2 * 1056;
        float val[2][2][4];
#pragma unroll
        for (int mt = 0; mt < 2; ++mt)
#pragma unroll
            for (int r = 0; r < 4; ++r) {
                const int row = mt * 16 + lg * 4 + r;
                const float bo = bl[mh * 32 + row];
                val[mt][0][r] = (mt ? acc10[r] : acc00[r]) + rp[row * 33 + lr] + bo;
                val[mt][1][r] = (mt ? acc11[r] : acc01[r]) + rp[row * 33 + 16 + lr] + bo;
            }
#pragma unroll
        for (int mt = 0; mt < 2; ++mt)
#pragma unroll
            for (int nt = 0; nt < 2; ++nt)
#pragma unroll
                for (int r = 0; r < 4; ++r)
                    Dt[(nt * 16 + lr) * 68 + mh * 32 + mt * 16 + lg * 4 + r] = val[mt][nt][r];

#pragma unroll
        for (int nt = 0; nt < 2; ++nt) {
            float m = val[0][nt][0], ls = 1.f;
            int a = r0 + mh * 32 + lg * 4;
#pragma unroll
            for (int q = 1; q < 8; ++q) {
                const int mt = q >> 2, r = q & 3;
                const float x = val[mt][nt][r];
                const int row = r0 + mh * 32 + mt * 16 + lg * 4 + r;
                if (x > m) { ls = ls * expf(m - x) + 1.f; m = x; a = row; }
                else       { ls += expf(x - m); }
            }
            sm_merge(m, ls, a, __shfl_xor(m, 16), __shfl_xor(ls, 16), __shfl_xor(a, 16));
            sm_merge(m, ls, a, __shfl_xor(m, 32), __shfl_xor(ls, 32), __shfl_xor(a, 32));
            if (lg == 0) { pm[mh][nt * 16 + lr] = m; pls[mh][nt * 16 + lr] = ls; pa[mh][nt * 16 + lr] = a; }
        }
    }
    __syncthreads();

    if (t < 32) {
        float m = pm[0][t], ls = pls[0][t]; int a = pa[0][t];
        sm_merge(m, ls, a, pm[1][t], pls[1][t], pa[1][t]);
        P[(size_t)t * 500 + blk] = make_float4(m, ls, (float)a, 0.f);   // P[b][tile]
    }

    const int sb = t >> 4, rq = t & 15;
    const f4v v = *(const f4v*)&Dt[sb * 68 + rq * 4];
    __builtin_nontemporal_store(v, (f4v*)&orow[(size_t)sb * V + r0 + rq * 4]);
}

// ---------------------------------------------------------------- FIN2: coalesced partials -> TOK, C, x
__global__ __launch_bounds__(256) void k_fin2(
    const float4* __restrict__ P, const float* __restrict__ emb,
    float* __restrict__ xG, float* __restrict__ C)
{
    const int b = blockIdx.x;
    const int t = threadIdx.x;
    __shared__ float fm[256], fl[256];
    __shared__ int   fa[256], stok;

    float m = NEG_INF, l = 0.f; int a = 0x7FFFFFFF;
    if (t < 500) {
        const float4 p = P[(size_t)b * 500 + t];
        m = p.x; l = p.y; a = (int)p.z;
    }
    if (t + 256 < 500) {
        const float4 p = P[(size_t)b * 500 + t + 256];
        sm_merge(m, l, a, p.x, p.y, (int)p.z);
    }
    fm[t] = m; fl[t] = l; fa[t] = a;
    __syncthreads();
    for (int s = 128; s > 0; s >>= 1) {
        if (t < s) {
            float mm = fm[t]; float ll = fl[t]; int aa = fa[t];
            sm_merge(mm, ll, aa, fm[t + s], fl[t + s], fa[t + s]);
            fm[t] = mm; fl[t] = ll; fa[t] = aa;
        }
        __syncthreads();
    }
    if (t == 0) {
        C[b] = fm[0] + logf(fl[0]);
        stok = fa[0];
    }
    __syncthreads();
    const int TOK = stok;
    for (int k = t; k < EMB; k += 256)
        xG[b * EMB + k] = tanhf(emb[(size_t)TOK * EMB + k]);
}

// ---------------------------------------------------------------- deferred subtract
__global__ __launch_bounds__(256) void k_sub(float* __restrict__ out,
                                             const float* __restrict__ C)
{
    const int r = blockIdx.x;
    const float c = C[r];
    f4v* row = (f4v*)(out + (size_t)r * V);
    for (int v = threadIdx.x; v < V / 4; v += 256) {
        f4v x = __builtin_nontemporal_load(&row[v]);
        x -= c;
        __builtin_nontemporal_store(x, &row[v]);
    }
}

// ---------------------------------------------------------------- launch
extern "C" void kernel_launch(void* const* d_in, const int* in_sizes, int n_in,
                              void* d_out, int out_size, void* d_ws, size_t ws_size,
                              hipStream_t stream)
{
    const float* p_ih   = (const float*)d_in[0];
    // d_in[1] encoder_outputs unused; d_in[2] tgt_len recovered from out_size
    const float* p_emb  = (const float*)d_in[3];
    const float* p_wih  = (const float*)d_in[4];
    const float* p_bih  = (const float*)d_in[5];
    const float* p_whh  = (const float*)d_in[6];
    const float* p_bhh  = (const float*)d_in[7];
    const float* p_wout = (const float*)d_in[8];
    const float* p_bout = (const float*)d_in[9];
    float* out = (float*)d_out;
    float* ws  = (float*)d_ws;
    const int T = out_size / (B * V);

    float*  xG  = ws + OFF_XG;
    float*  hA  = ws + OFF_HA;
    float*  hB  = ws + OFF_HB;
    float4* P   = (float4*)(ws + OFF_P);
    float*  C   = ws + OFF_C;
    short*  Hhi = (short*)(ws + OFF_HHI);
    short*  Hlo = (short*)(ws + OFF_HLO);
    float*  W3  = ws + OFF_W3;
    short*  Whi = (short*)(ws + OFF_WHI);
    short*  Wlo = (short*)(ws + OFF_WLO);

    k_init<<<2048, 256, 0, stream>>>(p_ih, p_emb, p_wout, p_wih, p_whh, ws);

    for (int st = 0; st < T; ++st) {
        float* hold = (st & 1) ? hB : hA;
        float* hnew = (st & 1) ? hA : hB;
        float* orow = out + (size_t)st * B * V;
        k_gru<<<256, 1024, 0, stream>>>(xG, hold, W3, p_bih, p_bhh,
                                        hnew, Hhi, Hlo);
        k_proj<<<500, 512, 0, stream>>>(Whi, Wlo, Hhi, Hlo, p_bout, orow, P);
        k_fin2<<<B, 256, 0, stream>>>(P, p_emb, xG, C + st * B);
    }
    k_sub<<<T * B, 256, 0, stream>>>(out, C);
}

// Round 18
// 3767.546 us; speedup vs baseline: 1.2564x; 1.2564x over previous
//
#include <hip/hip_runtime.h>
#include <math.h>

#define B    32
#define H    1024
#define EMB  512
#define V    32000
#define SOS  1

// ws float offsets (R15 layout). x/h state: [k][b], b contiguous.
#define OFF_X   0            // EMB*B
#define OFF_HA  16384        // H*B
#define OFF_HB  49152        // H*B
#define OFF_P   81920        // float4[500][32] = 64000 floats
#define OFF_C   145920       // T*B
#define OFF_HHI 147968       // short[H*B] (16384 floats)
#define OFF_HLO 164352       // short[H*B]
#define OFF_WHI 180736       // short[V*H] (16384000 floats)
#define OFF_WLO 16564736     // short[V*H]

#define NEG_INF (-3.0e38f)

typedef float f4v   __attribute__((ext_vector_type(4)));
typedef short short8v __attribute__((ext_vector_type(8)));
typedef float f32x4 __attribute__((ext_vector_type(4)));

#define MF(a,b,c) c = __builtin_amdgcn_mfma_f32_16x16x32_bf16(a, b, c, 0, 0, 0)

__device__ __forceinline__ unsigned short rnb(float x) {
    unsigned u = __float_as_uint(x);
    unsigned r = u + 0x7FFFu + ((u >> 16) & 1u);
    return (unsigned short)(r >> 16);
}
__device__ __forceinline__ float bfh(unsigned short s) {
    return __uint_as_float(((unsigned)s) << 16);
}
__device__ __forceinline__ void sm_merge(float& m, float& l, int& a,
                                         float om, float ol, int oa)
{
    const bool take = (om > m) || (om == m && oa < a);
    const float mn = take ? om : m;
    const int   an = take ? oa : a;
    l = l * expf(m - mn) + ol * expf(om - mn);
    m = mn; a = an;
}

// ---------------------------------------------------------------- INIT (+ W hi/lo split)
__global__ void k_init(const float* __restrict__ ih, const float* __restrict__ emb,
                       const float* __restrict__ wout, float* __restrict__ ws)
{
    const size_t idx = (size_t)blockIdx.x * blockDim.x + threadIdx.x;
    const size_t stride = (size_t)gridDim.x * blockDim.x;
    for (size_t i = idx; i < EMB * B; i += stride)
        ws[OFF_X + i] = tanhf(emb[(size_t)SOS * EMB + (i >> 5)]);
    short* Hhi = (short*)(ws + OFF_HHI);
    short* Hlo = (short*)(ws + OFF_HLO);
    for (size_t i = idx; i < H * B; i += stride) {
        int j = (int)(i >> 5), b = (int)(i & 31);
        const float hv = ih[(size_t)b * H + j];
        ws[OFF_HA + j * 32 + b] = hv;
        const unsigned short hi = rnb(hv);
        const int pidx = ((j >> 3) * 32 + b) * 8 + (j & 7);
        Hhi[pidx] = (short)hi;
        Hlo[pidx] = (short)rnb(hv - bfh(hi));
    }
    short* Whi = (short*)(ws + OFF_WHI);
    short* Wlo = (short*)(ws + OFF_WLO);
    for (size_t i = idx; i < (size_t)V * H; i += stride) {
        const float x = wout[i];
        const unsigned short hi = rnb(x);
        Whi[i] = (short)hi;
        Wlo[i] = (short)rnb(x - bfh(hi));
    }
}

// ---------------------------------------------------------------- GRU (R15 body, 16-way k-split)
// 512 blocks x 1024 thr (2 blocks/CU, 32 waves/CU). Block: 64 (j,b) pairs x 16 k-slices of 96.
__global__ __launch_bounds__(1024) void k_gru(
    const float* __restrict__ xG, const float* __restrict__ hold,
    const float* __restrict__ wih, const float* __restrict__ bih,
    const float* __restrict__ whh, const float* __restrict__ bhh,
    float* __restrict__ hnew, short* __restrict__ Hhi, short* __restrict__ Hlo)
{
    const int t   = threadIdx.x;
    const int blk = blockIdx.x;
    __shared__ float sred[4 * 1088];     // [gate][pl*17+ks], 17 coprime 32

    const int ks = t >> 6;               // 0..15
    const int pl = t & 63;
    const int p  = blk * 64 + pl;
    const int b  = p & 31;
    const int j  = p >> 5;

    float ar = 0.f, az = 0.f, ain = 0.f, ahn = 0.f;
    const int k0 = ks * 96, k1 = k0 + 96;

    const int xe = (k1 < EMB) ? k1 : EMB;
    for (int k = k0; k < xe; k += 4) {
        const float u0 = xG[(k + 0) * 32 + b];
        const float u1 = xG[(k + 1) * 32 + b];
        const float u2 = xG[(k + 2) * 32 + b];
        const float u3 = xG[(k + 3) * 32 + b];
        const float4 w0 = *(const float4*)&wih[(size_t)(0 * H + j) * EMB + k];
        const float4 w1 = *(const float4*)&wih[(size_t)(1 * H + j) * EMB + k];
        const float4 w2 = *(const float4*)&wih[(size_t)(2 * H + j) * EMB + k];
        ar  = fmaf(w0.x, u0, fmaf(w0.y, u1, fmaf(w0.z, u2, fmaf(w0.w, u3, ar))));
        az  = fmaf(w1.x, u0, fmaf(w1.y, u1, fmaf(w1.z, u2, fmaf(w1.w, u3, az))));
        ain = fmaf(w2.x, u0, fmaf(w2.y, u1, fmaf(w2.z, u2, fmaf(w2.w, u3, ain))));
    }
    const int hs = (k0 > EMB) ? k0 : EMB;
    for (int k = hs; k < k1; k += 4) {
        const int kh = k - EMB;
        const float u0 = hold[(kh + 0) * 32 + b];
        const float u1 = hold[(kh + 1) * 32 + b];
        const float u2 = hold[(kh + 2) * 32 + b];
        const float u3 = hold[(kh + 3) * 32 + b];
        const float4 w0 = *(const float4*)&whh[(size_t)(0 * H + j) * H + kh];
        const float4 w1 = *(const float4*)&whh[(size_t)(1 * H + j) * H + kh];
        const float4 w2 = *(const float4*)&whh[(size_t)(2 * H + j) * H + kh];
        ar  = fmaf(w0.x, u0, fmaf(w0.y, u1, fmaf(w0.z, u2, fmaf(w0.w, u3, ar))));
        az  = fmaf(w1.x, u0, fmaf(w1.y, u1, fmaf(w1.z, u2, fmaf(w1.w, u3, az))));
        ahn = fmaf(w2.x, u0, fmaf(w2.y, u1, fmaf(w2.z, u2, fmaf(w2.w, u3, ahn))));
    }

    sred[0 * 1088 + pl * 17 + ks] = ar;
    sred[1 * 1088 + pl * 17 + ks] = az;
    sred[2 * 1088 + pl * 17 + ks] = ain;
    sred[3 * 1088 + pl * 17 + ks] = ahn;
    __syncthreads();

    if (t < 64) {
        const int pp = blk * 64 + t;
        const int bb = pp & 31, jj = pp >> 5;
        float s0 = 0.f, s1 = 0.f, s2 = 0.f, s3 = 0.f;
#pragma unroll
        for (int q = 0; q < 16; ++q) {
            s0 += sred[0 * 1088 + t * 17 + q];
            s1 += sred[1 * 1088 + t * 17 + q];
            s2 += sred[2 * 1088 + t * 17 + q];
            s3 += sred[3 * 1088 + t * 17 + q];
        }
        float gr  = s0 + bih[jj]         + bhh[jj];
        float gz  = s1 + bih[H + jj]     + bhh[H + jj];
        float gin = s2 + bih[2 * H + jj];
        float ghn = s3 + bhh[2 * H + jj];
        float r = 1.f / (1.f + expf(-gr));
        float z = 1.f / (1.f + expf(-gz));
        float n = tanhf(gin + r * ghn);   // r multiplies hh-part only
        const int hidx = jj * 32 + bb;
        const float hv = (1.f - z) * n + z * hold[hidx];
        hnew[hidx] = hv;
        const unsigned short hi = rnb(hv);
        const unsigned short lo = rnb(hv - bfh(hi));
        const int pidx = ((jj >> 3) * 32 + bb) * 8 + (jj & 7);
        Hhi[pidx] = (short)hi;
        Hlo[pidx] = (short)lo;
    }
}

// ---------------------------------------------------------------- PROJ via bf16-MFMA (3-pass) — R15 body
__global__ __launch_bounds__(512, 4) void k_proj(
    const short* __restrict__ Whi, const short* __restrict__ Wlo,
    const short* __restrict__ Hhi, const short* __restrict__ Hlo,
    const float* __restrict__ bout, float* __restrict__ orow,
    float4* __restrict__ P)
{
    __shared__ float Red[4 * 32 * 33];
    __shared__ float Dt[32 * 68];
    __shared__ float bl[64];
    __shared__ float pm[2][32], pls[2][32];
    __shared__ int   pa[2][32];

    const int t   = threadIdx.x;
    const int blk = blockIdx.x;
    const int r0  = blk * 64;
    const int w   = t >> 6;
    const int mh  = w >> 2;
    const int kq  = w & 3;
    const int l   = t & 63;
    const int lr  = l & 15;
    const int lg  = l >> 4;

    if (t < 64) bl[t] = bout[r0 + t];

    const short* pAh = Whi + (size_t)(r0 + mh * 32 + lr) * H + lg * 8;
    const short* pAl = Wlo + (size_t)(r0 + mh * 32 + lr) * H + lg * 8;
    const short* pBh = Hhi + ((size_t)lg * 32 + lr) * 8;
    const short* pBl = Hlo + ((size_t)lg * 32 + lr) * 8;

    f32x4 acc00 = {0.f, 0.f, 0.f, 0.f};
    f32x4 acc01 = {0.f, 0.f, 0.f, 0.f};
    f32x4 acc10 = {0.f, 0.f, 0.f, 0.f};
    f32x4 acc11 = {0.f, 0.f, 0.f, 0.f};

#pragma unroll 2
    for (int i = 0; i < 8; ++i) {
        const int c = 4 * i + kq;
        const short8v a0h = *(const short8v*)(pAh + c * 32);
        const short8v a0l = *(const short8v*)(pAl + c * 32);
        const short8v a1h = *(const short8v*)(pAh + 16 * H + c * 32);
        const short8v a1l = *(const short8v*)(pAl + 16 * H + c * 32);
        const short8v b0h = *(const short8v*)(pBh + c * 1024);
        const short8v b0l = *(const short8v*)(pBl + c * 1024);
        const short8v b1h = *(const short8v*)(pBh + c * 1024 + 128);
        const short8v b1l = *(const short8v*)(pBl + c * 1024 + 128);
        MF(a0h, b0h, acc00); MF(a0h, b0l, acc00); MF(a0l, b0h, acc00);
        MF(a0h, b1h, acc01); MF(a0h, b1l, acc01); MF(a0l, b1h, acc01);
        MF(a1h, b0h, acc10); MF(a1h, b0l, acc10); MF(a1l, b0h, acc10);
        MF(a1h, b1h, acc11); MF(a1h, b1l, acc11); MF(a1l, b1h, acc11);
    }

    if (kq >= 2) {
        float* rp = Red + (mh * 2 + (kq - 2)) * 1056;
#pragma unroll
        for (int mt = 0; mt < 2; ++mt)
#pragma unroll
            for (int r = 0; r < 4; ++r) {
                const int row = mt * 16 + lg * 4 + r;
                rp[row * 33 + lr]      = mt ? acc10[r] : acc00[r];
                rp[row * 33 + 16 + lr] = mt ? acc11[r] : acc01[r];
            }
    }
    __syncthreads();
    if (kq < 2) {
        const float* rp = Red + (mh * 2 + kq) * 1056;
#pragma unroll
        for (int mt = 0; mt < 2; ++mt)
#pragma unroll
            for (int r = 0; r < 4; ++r) {
                const int row = mt * 16 + lg * 4 + r;
                const float e0 = rp[row * 33 + lr];
                const float e1 = rp[row * 33 + 16 + lr];
                if (mt) { acc10[r] += e0; acc11[r] += e1; }
                else    { acc00[r] += e0; acc01[r] += e1; }
            }
    }
    __syncthreads();
    if (kq == 1) {
        float* rp = Red + mh * 2 * 1056;
#pragma unroll
        for (int mt = 0; mt < 2; ++mt)
#pragma unroll
            for (int r = 0; r < 4; ++r) {
                const int row = mt * 16 + lg * 4 + r;
                rp[row * 33 + lr]      = mt ? acc10[r] : acc00[r];
                rp[row * 33 + 16 + lr] = mt ? acc11[r] : acc01[r];
            }
    }
    __syncthreads();

    if (kq == 0) {
        const float* rp = Red + mh * 2 * 1056;
        float val[2][2][4];
#pragma unroll
        for (int mt = 0; mt < 2; ++mt)
#pragma unroll
            for (int r = 0; r < 4; ++r) {
                const int row = mt * 16 + lg * 4 + r;
                const float bo = bl[mh * 32 + row];
                val[mt][0][r] = (mt ? acc10[r] : acc00[r]) + rp[row * 33 + lr] + bo;
                val[mt][1][r] = (mt ? acc11[r] : acc01[r]) + rp[row * 33 + 16 + lr] + bo;
            }
#pragma unroll
        for (int mt = 0; mt < 2; ++mt)
#pragma unroll
            for (int nt = 0; nt < 2; ++nt)
#pragma unroll
                for (int r = 0; r < 4; ++r)
                    Dt[(nt * 16 + lr) * 68 + mh * 32 + mt * 16 + lg * 4 + r] = val[mt][nt][r];

#pragma unroll
        for (int nt = 0; nt < 2; ++nt) {
            float m = val[0][nt][0], ls = 1.f;
            int a = r0 + mh * 32 + lg * 4;
#pragma unroll
            for (int q = 1; q < 8; ++q) {
                const int mt = q >> 2, r = q & 3;
                const float x = val[mt][nt][r];
                const int row = r0 + mh * 32 + mt * 16 + lg * 4 + r;
                if (x > m) { ls = ls * expf(m - x) + 1.f; m = x; a = row; }
                else       { ls += expf(x - m); }
            }
            sm_merge(m, ls, a, __shfl_xor(m, 16), __shfl_xor(ls, 16), __shfl_xor(a, 16));
            sm_merge(m, ls, a, __shfl_xor(m, 32), __shfl_xor(ls, 32), __shfl_xor(a, 32));
            if (lg == 0) { pm[mh][nt * 16 + lr] = m; pls[mh][nt * 16 + lr] = ls; pa[mh][nt * 16 + lr] = a; }
        }
    }
    __syncthreads();

    if (t < 32) {
        float m = pm[0][t], ls = pls[0][t]; int a = pa[0][t];
        sm_merge(m, ls, a, pm[1][t], pls[1][t], pa[1][t]);
        P[blk * 32 + t] = make_float4(m, ls, (float)a, 0.f);
    }

    const int sb = t >> 4, rq = t & 15;
    const f4v v = *(const f4v*)&Dt[sb * 68 + rq * 4];
    __builtin_nontemporal_store(v, (f4v*)&orow[(size_t)sb * V + r0 + rq * 4]);
}

// ---------------------------------------------------------------- FIN2: 500 partials -> TOK, C, xG
__global__ __launch_bounds__(256) void k_fin2(
    const float4* __restrict__ partial, const float* __restrict__ emb,
    float* __restrict__ xG, float* __restrict__ C)
{
    const int b = blockIdx.x;
    const int t = threadIdx.x;
    __shared__ float fm[256], fl[256];
    __shared__ int   fa[256], stok;

    float m = NEG_INF, l = 0.f; int a = 0x7FFFFFFF;
    {
        float4 p = partial[t * 32 + b];
        m = p.x; l = p.y; a = (int)p.z;
    }
    if (t + 256 < 500) {
        float4 p = partial[(t + 256) * 32 + b];
        sm_merge(m, l, a, p.x, p.y, (int)p.z);
    }
    fm[t] = m; fl[t] = l; fa[t] = a;
    __syncthreads();
    for (int s = 128; s > 0; s >>= 1) {
        if (t < s) {
            float mm = fm[t]; float ll = fl[t]; int aa = fa[t];
            sm_merge(mm, ll, aa, fm[t + s], fl[t + s], fa[t + s]);
            fm[t] = mm; fl[t] = ll; fa[t] = aa;
        }
        __syncthreads();
    }
    if (t == 0) {
        C[b] = fm[0] + logf(fl[0]);
        stok = fa[0];
    }
    __syncthreads();
    const int TOK = stok;
    for (int k = t; k < EMB; k += 256)
        xG[k * 32 + b] = tanhf(emb[(size_t)TOK * EMB + k]);
}

// ---------------------------------------------------------------- deferred subtract
__global__ __launch_bounds__(256) void k_sub(float* __restrict__ out,
                                             const float* __restrict__ C)
{
    const int r = blockIdx.x;
    const float c = C[r];
    f4v* row = (f4v*)(out + (size_t)r * V);
    for (int v = threadIdx.x; v < V / 4; v += 256) {
        f4v x = __builtin_nontemporal_load(&row[v]);
        x -= c;
        __builtin_nontemporal_store(x, &row[v]);
    }
}

// ---------------------------------------------------------------- launch
extern "C" void kernel_launch(void* const* d_in, const int* in_sizes, int n_in,
                              void* d_out, int out_size, void* d_ws, size_t ws_size,
                              hipStream_t stream)
{
    const float* p_ih   = (const float*)d_in[0];
    // d_in[1] encoder_outputs unused; d_in[2] tgt_len recovered from out_size
    const float* p_emb  = (const float*)d_in[3];
    const float* p_wih  = (const float*)d_in[4];
    const float* p_bih  = (const float*)d_in[5];
    const float* p_whh  = (const float*)d_in[6];
    const float* p_bhh  = (const float*)d_in[7];
    const float* p_wout = (const float*)d_in[8];
    const float* p_bout = (const float*)d_in[9];
    float* out = (float*)d_out;
    float* ws  = (float*)d_ws;
    const int T = out_size / (B * V);

    float*  xG  = ws + OFF_X;
    float*  hA  = ws + OFF_HA;
    float*  hB  = ws + OFF_HB;
    float4* P   = (float4*)(ws + OFF_P);
    float*  C   = ws + OFF_C;
    short*  Hhi = (short*)(ws + OFF_HHI);
    short*  Hlo = (short*)(ws + OFF_HLO);
    short*  Whi = (short*)(ws + OFF_WHI);
    short*  Wlo = (short*)(ws + OFF_WLO);

    k_init<<<2048, 256, 0, stream>>>(p_ih, p_emb, p_wout, ws);

    for (int st = 0; st < T; ++st) {
        float* hold = (st & 1) ? hB : hA;
        float* hnew = (st & 1) ? hA : hB;
        float* orow = out + (size_t)st * B * V;
        k_gru<<<512, 1024, 0, stream>>>(xG, hold, p_wih, p_bih, p_whh, p_bhh,
                                        hnew, Hhi, Hlo);
        k_proj<<<500, 512, 0, stream>>>(Whi, Wlo, Hhi, Hlo, p_bout, orow, P);
        k_fin2<<<B, 256, 0, stream>>>(P, p_emb, xG, C + st * B);
    }
    k_sub<<<T * B, 256, 0, stream>>>(out, C);
}